// Round 18
// baseline (344.019 us; speedup 1.0000x reference)
//
#include <hip/hip_runtime.h>
#include <hip/hip_bf16.h>

#define B_ 16
#define T_ 12
#define N_ 2000
#define E_ 8000
#define M_ 32000                 // B_*N_
#define EG (E_ + N_)             // 10000 edges per graph incl self loops
#define D_ 64

typedef __hip_bfloat16 bf16;
typedef unsigned short u16;
typedef __attribute__((ext_vector_type(8))) _Float16 half8;
typedef __attribute__((ext_vector_type(2))) _Float16 h2v;
typedef __attribute__((ext_vector_type(4))) float f32x4;

__device__ __forceinline__ float bfu(u16 u){ return __uint_as_float(((unsigned int)u)<<16); }
__device__ __forceinline__ u16 f2bu(float f){
  unsigned int x = __float_as_uint(f);
  x += 0x7FFFu + ((x >> 16) & 1u);
  return (u16)(x >> 16);
}
__device__ __forceinline__ u16 f2h(float f){
  _Float16 h = (_Float16)f; u16 r; __builtin_memcpy(&r, &h, 2); return r;
}
__device__ __forceinline__ float h2f(u16 u){
  _Float16 h; __builtin_memcpy(&h, &u, 2); return (float)h;
}
__device__ __forceinline__ h2v u2h(unsigned u){ h2v r; __builtin_memcpy(&r,&u,4); return r; }

// bijective XCD-aware block swizzle (m204 form): contiguous work chunk per XCD.
__device__ __forceinline__ int xcd_swz(int x, int n){
  int q = n>>3, r = n&7;
  int xcd = x&7, idx = x>>3;
  int base = (xcd<r) ? xcd*(q+1) : r*(q+1) + (xcd-r)*q;
  return base + idx;
}

// ---------------- weight prep: f16 MFMA fragments + PE table ----------------
__global__ void k_prep(const float* __restrict__ Wqkv, const float* __restrict__ Wo,
                       const float* __restrict__ Wf1, const float* __restrict__ Wf2,
                       const float* __restrict__ W2g,
                       u16* __restrict__ wqB, u16* __restrict__ woB,
                       u16* __restrict__ w1B, u16* __restrict__ w2B,
                       float* __restrict__ peT, u16* __restrict__ w2gB){
  int i = blockIdx.x*256 + threadIdx.x;    // 268 blocks
  if(i < 24576){
    int l=i/12288, r=i-l*12288;
    int nt=r>>10, r2=r&1023, c=r2>>9, r3=r2&511, lane=r3>>3, jj=r3&7;
    int m=lane&15, q=lane>>4;
    wqB[i] = f2h(Wqkv[l*12288 + (nt*16+m)*64 + c*32 + q*8 + jj]);
  } else if(i < 32768){
    int k2=i-24576;
    int l=k2>>12, r=k2&4095;
    int nt=r>>10, r2=r&1023, c=r2>>9, r3=r2&511, lane=r3>>3, jj=r3&7;
    int m=lane&15, q=lane>>4;
    woB[k2] = f2h(Wo[l*4096 + (nt*16+m)*64 + c*32 + q*8 + jj]);
  } else if(i < 49152){
    int k2=i-32768;
    int l=k2>>13, r=k2&8191;
    int nt=r>>10, r2=r&1023, c=r2>>9, r3=r2&511, lane=r3>>3, jj=r3&7;
    int m=lane&15, q=lane>>4;
    w1B[k2] = f2h(Wf1[l*8192 + (nt*16+m)*64 + c*32 + q*8 + jj]);
  } else if(i < 65536){
    int k2=i-49152;
    int l=k2>>13, r=k2&8191;
    int nt=r>>11, r2=r&2047, c=r2>>9, r3=r2&511, lane=r3>>3, jj=r3&7;
    int m=lane&15, q=lane>>4;
    w2B[k2] = f2h(Wf2[l*8192 + (nt*16+m)*128 + c*32 + q*8 + jj]);
  } else {
    int i2 = i - 65536;
    if(i2 < 768){
      int t=i2>>6, ch=i2&63;
      float ang = (float)t * __expf(-0.14391156463f * (float)(ch & ~1));
      peT[i2] = (ch&1) ? __cosf(ang) : __sinf(ang);
    } else if(i2 < 768+2048){
      // GAT2 W2 [32][64] as dual frags: elem j = W2[q*8+j][nt*16+m]
      int i3 = i2-768;
      int nt=i3>>9, r=i3&511, lane=r>>3, j=r&7;
      int m=lane&15, q=lane>>4;
      w2gB[i3] = f2h(W2g[(q*8+j)*64 + nt*16 + m]);
    }
  }
}

// ---------------- CSR build (ONE graph -- identical for all b,t) ----------------
__global__ void k_histg(const int* __restrict__ ei, int* __restrict__ deg){
  int e = blockIdx.x*256 + threadIdx.x; if(e>=EG) return;
  int dst = (e < E_) ? ei[E_+e] : e - E_;
  atomicAdd(&deg[dst], 1);
}

// single-block inclusive scan over 2000 degrees -> offs[0..2000]
__global__ __launch_bounds__(1024) void k_scang(const int* __restrict__ deg, int* __restrict__ offs){
  __shared__ int s[2048];
  int tid = threadIdx.x;
  s[tid]      = (tid      < N_) ? deg[tid]      : 0;
  s[tid+1024] = (tid+1024 < N_) ? deg[tid+1024] : 0;
  __syncthreads();
  for(int off=1; off<2048; off<<=1){
    int a0 = (tid>=off)      ? s[tid-off]      : 0;
    int a1 = (tid+1024>=off) ? s[tid+1024-off] : 0;
    __syncthreads();
    s[tid] += a0; s[tid+1024] += a1;
    __syncthreads();
  }
  if(tid      < N_) offs[tid+1]      = s[tid];
  if(tid+1024 < N_) offs[tid+1024+1] = s[tid+1024];
  if(tid==0) offs[0]=0;
}

__global__ void k_scatg(const int* __restrict__ ei, const int* __restrict__ offs,
                        int* __restrict__ cursor, int* __restrict__ csr){
  int e = blockIdx.x*256 + threadIdx.x; if(e>=EG) return;
  int srcl, dst;
  if(e < E_){ srcl = ei[e]; dst = ei[E_+e]; }
  else      { srcl = e - E_; dst = e - E_; }
  int pos = atomicAdd(&cursor[dst], 1);
  csr[offs[dst]+pos] = srcl;
}

// ---------------- fused GAT1 + GAT2 feature/score (MFMA) ----------------
// Round-11 measured form (UNCHANGED). Lane q*16+m: node m, head q; edge loop
// 4-way over q-lanes; operand-swapped MFMAs; packed stores; XCD swizzle.
__global__ __launch_bounds__(256) void k_gat12(
  const float* __restrict__ x_seq, const float* __restrict__ W1,
  const float* __restrict__ as1, const float* __restrict__ ad1, const float* __restrict__ b1,
  const float* __restrict__ as2, const float* __restrict__ ad2,
  const int* __restrict__ offs, const int* __restrict__ csr,
  const u16* __restrict__ w2gB,
  u16* __restrict__ h2u, float* __restrict__ asc, float* __restrict__ adc)
{
  int tid = threadIdx.x, w = tid>>6, lane = tid&63;
  int m = lane&15, q = lane>>4;
  int t = blockIdx.y;
  int bx = xcd_swz(blockIdx.x, 500);
  int node = bx*64 + w*16 + m;
  unsigned un=(unsigned)node, b=un/N_, n=un-b*N_;

  const half8* wb = (const half8*)w2gB;
  half8 w2f0 = wb[0*64+lane], w2f1 = wb[1*64+lane],
        w2f2 = wb[2*64+lane], w2f3 = wb[3*64+lane];

  float sS[4], sD[4];
  #pragma unroll
  for(int h=0;h<4;h++){
    float a=0.f, d=0.f;
    #pragma unroll
    for(int c=0;c<8;c++){ float wv=W1[h*8+c]; a+=wv*as1[h*8+c]; d+=wv*ad1[h*8+c]; }
    sS[h]=a; sD[h]=d;
  }

  const float* xsl = x_seq + (size_t)(b*T_+t)*N_;
  float xm = xsl[n];
  int e0=offs[n], e1=offs[n+1];
  float sum[4]={0.f,0.f,0.f,0.f}, ax[4]={0.f,0.f,0.f,0.f};
  for(int e=e0+q; e<e1; e+=4){
    float xv = xsl[csr[e]];
    #pragma unroll
    for(int h=0;h<4;h++){
      float ee = xv*sS[h] + xm*sD[h]; ee = ee>0.f ? ee : 0.2f*ee;
      float wv = __expf(ee); sum[h]+=wv; ax[h]+=wv*xv;
    }
  }
  #pragma unroll
  for(int h=0;h<4;h++){
    sum[h] += __shfl_xor(sum[h],16); sum[h] += __shfl_xor(sum[h],32);
    ax[h]  += __shfl_xor(ax[h],16);  ax[h]  += __shfl_xor(ax[h],32);
  }
  float A = ax[q]/(sum[q]+1e-16f);

  half8 af;
  #pragma unroll
  for(int j=0;j<8;j++){
    float v = A*W1[q*8+j] + b1[q*8+j]; v = v>0.f?v:0.f;
    af[j] = (_Float16)v;
  }
  f32x4 ac0={0.f,0.f,0.f,0.f}, ac1=ac0, ac2=ac0, ac3=ac0;
  ac0 = __builtin_amdgcn_mfma_f32_16x16x32_f16(w2f0, af, ac0,0,0,0);
  ac1 = __builtin_amdgcn_mfma_f32_16x16x32_f16(w2f1, af, ac1,0,0,0);
  ac2 = __builtin_amdgcn_mfma_f32_16x16x32_f16(w2f2, af, ac2,0,0,0);
  ac3 = __builtin_amdgcn_mfma_f32_16x16x32_f16(w2f3, af, ac3,0,0,0);

  size_t nd = (size_t)t*M_ + node;
  u16* row = h2u + nd*64;
  {
    uint2 p;
    p.x = (unsigned)f2bu(ac0[0]) | ((unsigned)f2bu(ac0[1])<<16);
    p.y = (unsigned)f2bu(ac0[2]) | ((unsigned)f2bu(ac0[3])<<16);
    *(uint2*)(row + 0*16 + q*4) = p;
    p.x = (unsigned)f2bu(ac1[0]) | ((unsigned)f2bu(ac1[1])<<16);
    p.y = (unsigned)f2bu(ac1[2]) | ((unsigned)f2bu(ac1[3])<<16);
    *(uint2*)(row + 1*16 + q*4) = p;
    p.x = (unsigned)f2bu(ac2[0]) | ((unsigned)f2bu(ac2[1])<<16);
    p.y = (unsigned)f2bu(ac2[2]) | ((unsigned)f2bu(ac2[3])<<16);
    *(uint2*)(row + 2*16 + q*4) = p;
    p.x = (unsigned)f2bu(ac3[0]) | ((unsigned)f2bu(ac3[1])<<16);
    p.y = (unsigned)f2bu(ac3[2]) | ((unsigned)f2bu(ac3[3])<<16);
    *(uint2*)(row + 3*16 + q*4) = p;
  }

  const float* a2sp = as2 + q*4;
  const float* a2dp = ad2 + q*4;
  float ps[4], pd[4];
  ps[0]=ac0[0]*a2sp[ 0]+ac0[1]*a2sp[ 1]+ac0[2]*a2sp[ 2]+ac0[3]*a2sp[ 3];
  ps[1]=ac1[0]*a2sp[16]+ac1[1]*a2sp[17]+ac1[2]*a2sp[18]+ac1[3]*a2sp[19];
  ps[2]=ac2[0]*a2sp[32]+ac2[1]*a2sp[33]+ac2[2]*a2sp[34]+ac2[3]*a2sp[35];
  ps[3]=ac3[0]*a2sp[48]+ac3[1]*a2sp[49]+ac3[2]*a2sp[50]+ac3[3]*a2sp[51];
  pd[0]=ac0[0]*a2dp[ 0]+ac0[1]*a2dp[ 1]+ac0[2]*a2dp[ 2]+ac0[3]*a2dp[ 3];
  pd[1]=ac1[0]*a2dp[16]+ac1[1]*a2dp[17]+ac1[2]*a2dp[18]+ac1[3]*a2dp[19];
  pd[2]=ac2[0]*a2dp[32]+ac2[1]*a2dp[33]+ac2[2]*a2dp[34]+ac2[3]*a2dp[35];
  pd[3]=ac3[0]*a2dp[48]+ac3[1]*a2dp[49]+ac3[2]*a2dp[50]+ac3[3]*a2dp[51];
  #pragma unroll
  for(int h=0;h<4;h++){
    ps[h] += __shfl_xor(ps[h],16); ps[h] += __shfl_xor(ps[h],32);
    pd[h] += __shfl_xor(pd[h],16); pd[h] += __shfl_xor(pd[h],32);
  }
  float ra = (q&1) ? ((q&2)? ps[3]:ps[1]) : ((q&2)? ps[2]:ps[0]);
  float rd = (q&1) ? ((q&2)? pd[3]:pd[1]) : ((q&2)? pd[2]:pd[0]);
  asc[nd*4+q] = ra;
  adc[nd*4+q] = rd;
}

// ---------------- GAT2 softmax-aggregate + bias + relu + PE(table); f16 out ------
// Round-18: 4-WAY edge split (16 threads per node: j in 0..3, h in 0..3).
// Serial chain 2.5 -> 1.25 iterations (gat2b diagnosed chain-latency-bound:
// r6 width-null, r7/r8 chain-cut wins). Merge via shfl_xor(4)+shfl_xor(8)
// within the 16-lane node group; each lane writes its 4-channel quarter.
// Slice-major XCD mapping preserved: 24000 blocks = 8 XCDs x 24 slices x 125;
// 125 blocks x 16 nodes = 2000 exactly (no masking).
__global__ __launch_bounds__(256) void k_gat2b(
  const u16* __restrict__ h2u, const float* __restrict__ asc, const float* __restrict__ adc,
  const float* __restrict__ b2, const int* __restrict__ offs, const int* __restrict__ csr,
  const float* __restrict__ peT, u16* __restrict__ seq)
{
  int x = blockIdx.x;
  int xcd = x&7, idx = x>>3;          // idx in [0,3000)
  int work = xcd*3000 + idx;          // contiguous slice-major work per XCD
  int slice = work/125;               // [0,192)
  int local = work - slice*125;       // [0,125)
  int b = slice/12, t = slice - b*12;
  int tid = threadIdx.x;
  int nl = local*16 + (tid>>4);       // local node in [0,2000)
  int j = (tid>>2)&3, h = tid&3;

  size_t base_s = (size_t)t*M_ + (size_t)b*N_;   // csr holds local indices
  float am = adc[(base_s + nl)*4+h];
  int e0=offs[nl], e1=offs[nl+1];
  float sum=0.f;
  float A[16];
  #pragma unroll
  for(int c=0;c<16;c++) A[c]=0.f;
  for(int e=e0+j; e<e1; e+=4){
    size_t s = base_s + (unsigned)csr[e];
    float w = asc[s*4+h] + am; w = w>0.f ? w : 0.2f*w;
    w = __expf(w); sum += w;
    const uint4* hp = (const uint4*)(h2u + s*64 + h*16);
    uint4 p0 = hp[0], p1 = hp[1];
    A[ 0] += w*bfu((u16)(p0.x)); A[ 1] += w*bfu((u16)(p0.x>>16));
    A[ 2] += w*bfu((u16)(p0.y)); A[ 3] += w*bfu((u16)(p0.y>>16));
    A[ 4] += w*bfu((u16)(p0.z)); A[ 5] += w*bfu((u16)(p0.z>>16));
    A[ 6] += w*bfu((u16)(p0.w)); A[ 7] += w*bfu((u16)(p0.w>>16));
    A[ 8] += w*bfu((u16)(p1.x)); A[ 9] += w*bfu((u16)(p1.x>>16));
    A[10] += w*bfu((u16)(p1.y)); A[11] += w*bfu((u16)(p1.y>>16));
    A[12] += w*bfu((u16)(p1.z)); A[13] += w*bfu((u16)(p1.z>>16));
    A[14] += w*bfu((u16)(p1.w)); A[15] += w*bfu((u16)(p1.w>>16));
  }
  // merge the four edge-quarters (partners tid^4, tid^8; same 16-lane group)
  sum += __shfl_xor(sum,4);
  #pragma unroll
  for(int c=0;c<16;c++) A[c] += __shfl_xor(A[c],4);
  sum += __shfl_xor(sum,8);
  #pragma unroll
  for(int c=0;c<16;c++) A[c] += __shfl_xor(A[c],8);

  float inv = 1.f/(sum + 1e-16f);
  u16 ov[4];
  #pragma unroll
  for(int c=0;c<4;c++){
    int ch = h*16 + j*4 + c;
    float v = A[j*4+c]*inv + b2[ch]; v = v>0.f ? v : 0.f;
    ov[c] = f2h(v + peT[t*64+ch]);
  }
  uint2 o;
  o.x = (unsigned)ov[0] | ((unsigned)ov[1]<<16);
  o.y = (unsigned)ov[2] | ((unsigned)ov[3]<<16);
  *(uint2*)(seq + (base_s + nl)*64 + h*16 + j*4) = o;
}

// ---------------- BOTH transformer layers + fused head -------------------------
// Round-15 measured optimum: __launch_bounds__(192,4) (VGPR 64, occ 38%,
// 168us steady). Weight-LDS-staging (r16): occ 16% -> 275us -- kernel is
// latency/occupancy-bound; do NOT add LDS or registers. Operand swap (x2),
// xres registers, gat2b fusion all regressed. Body UNCHANGED since round 4.
__global__ __launch_bounds__(192, 4) void k_layer2(
  const u16* __restrict__ seq,
  const u16* __restrict__ wqB, const u16* __restrict__ woB,
  const u16* __restrict__ w1B, const u16* __restrict__ w2B,
  const float* __restrict__ bqkv, const float* __restrict__ bo,
  const float* __restrict__ bf1,  const float* __restrict__ bf2,
  const float* __restrict__ g1,   const float* __restrict__ be1,
  const float* __restrict__ g2,   const float* __restrict__ be2,
  const float* __restrict__ Wh,   const float* __restrict__ bh,
  float* __restrict__ out)
{
  __shared__ __align__(16) u16 X[3456];      // [48][72] f16
  __shared__ __align__(16) u16 QKV[10368];   // [3][48][72]
  u16* Hd = QKV + 3456;                      // H[48][136] overlays K,V
  int tid=threadIdx.x, w=tid>>6, lane=tid&63;
  int m=lane&15, q=lane>>4;
  int r = w*16 + m;

  // stage X: wave w loads its own 16 rows (wave-private, no barrier needed).
  #pragma unroll
  for(int half=0; half<2; half++){
    int rr = half*8 + (lane>>3);
    int row = w*16 + rr;
    int nn = row/12, tt = row-nn*12;
    const uint4* src = (const uint4*)(seq + ((size_t)tt*M_ + (size_t)blockIdx.x*4+nn)*64) + (lane&7);
    *((uint4*)&X[row*72] + (lane&7)) = *src;
  }

  #pragma unroll 1
  for(int l=0; l<2; l++){
    const half8* wqv = (const half8*)(wqB + (size_t)l*12288);
    const half8* wov = (const half8*)(woB + (size_t)l*4096);
    const half8* w1v = (const half8*)(w1B + (size_t)l*8192);
    const half8* w2v = (const half8*)(w2B + (size_t)l*8192);
    const float* bq = bqkv + l*192;
    const float* boL = bo + l*64;
    const float* b1L = bf1 + l*128;
    const float* b2L = bf2 + l*64;
    const float* g1L = g1 + l*64, *be1L = be1 + l*64;
    const float* g2L = g2 + l*64, *be2L = be2 + l*64;

    // ---- QKV projection: A-frags from X (wave-own rows) ----
    half8 xa0 = *(const half8*)&X[r*72 + q*8];
    half8 xa1 = *(const half8*)&X[r*72 + 32 + q*8];
    #pragma unroll
    for(int nt=0; nt<12; nt++){
      f32x4 acc={0.f,0.f,0.f,0.f};
      acc = __builtin_amdgcn_mfma_f32_16x16x32_f16(xa0, wqv[(nt*2+0)*64+lane], acc,0,0,0);
      acc = __builtin_amdgcn_mfma_f32_16x16x32_f16(xa1, wqv[(nt*2+1)*64+lane], acc,0,0,0);
      int cg = nt*16+m; float bias = bq[cg];
      int s = nt>>2, lc = cg&63;
      #pragma unroll
      for(int rg=0;rg<4;rg++){
        int row = w*16 + q*4 + rg;
        QKV[s*3456 + row*72 + lc] = f2h(acc[rg]+bias);
      }
    }
    __syncthreads();

    // ---- attention: 192 lanes = (node an, head ah, time at); fdot2 + pk_fma ----
    {
      int an = tid/48, rem = tid - an*48;
      int ah = rem/12, at = rem - ah*12;
      u16* qrow = &QKV[(an*12+at)*72 + ah*16];
      uint4 qa = ((const uint4*)qrow)[0], qb = ((const uint4*)qrow)[1];
      float s[12];
      #pragma unroll
      for(int t2=0;t2<12;t2++){
        const uint4* kp = (const uint4*)&QKV[3456 + (an*12+t2)*72 + ah*16];
        uint4 ka=kp[0], kb=kp[1];
        float d=0.f;
        d=__builtin_amdgcn_fdot2(u2h(qa.x),u2h(ka.x),d,false);
        d=__builtin_amdgcn_fdot2(u2h(qa.y),u2h(ka.y),d,false);
        d=__builtin_amdgcn_fdot2(u2h(qa.z),u2h(ka.z),d,false);
        d=__builtin_amdgcn_fdot2(u2h(qa.w),u2h(ka.w),d,false);
        d=__builtin_amdgcn_fdot2(u2h(qb.x),u2h(kb.x),d,false);
        d=__builtin_amdgcn_fdot2(u2h(qb.y),u2h(kb.y),d,false);
        d=__builtin_amdgcn_fdot2(u2h(qb.z),u2h(kb.z),d,false);
        d=__builtin_amdgcn_fdot2(u2h(qb.w),u2h(kb.w),d,false);
        s[t2] = d*0.25f;
      }
      float mx=s[0];
      #pragma unroll
      for(int t2=1;t2<12;t2++) mx=fmaxf(mx,s[t2]);
      float sum=0.f;
      #pragma unroll
      for(int t2=0;t2<12;t2++){ s[t2]=__expf(s[t2]-mx); sum+=s[t2]; }
      float inv=1.f/sum;
      half8 o0, o1;
      #pragma unroll
      for(int i=0;i<8;i++){ o0[i]=(_Float16)0.f; o1[i]=(_Float16)0.f; }
      #pragma unroll
      for(int t2=0;t2<12;t2++){
        const half8* vr = (const half8*)&QKV[6912 + (an*12+t2)*72 + ah*16];
        _Float16 wh = (_Float16)s[t2];
        o0 += vr[0]*wh; o1 += vr[1]*wh;
      }
      _Float16 ih = (_Float16)inv;
      ((half8*)qrow)[0]=o0*ih; ((half8*)qrow)[1]=o1*ih;
    }
    __syncthreads();

    // ---- Wo + residual(X) + LN1 ----
    half8 oa0 = *(const half8*)&QKV[r*72 + q*8];
    half8 oa1 = *(const half8*)&QKV[r*72 + 32 + q*8];
    float y[4][4];
    #pragma unroll
    for(int nt=0;nt<4;nt++){
      f32x4 acc={0.f,0.f,0.f,0.f};
      acc = __builtin_amdgcn_mfma_f32_16x16x32_f16(oa0, wov[(nt*2+0)*64+lane], acc,0,0,0);
      acc = __builtin_amdgcn_mfma_f32_16x16x32_f16(oa1, wov[(nt*2+1)*64+lane], acc,0,0,0);
      int col=nt*16+m; float bias=boL[col];
      #pragma unroll
      for(int rg=0;rg<4;rg++)
        y[nt][rg] = acc[rg] + bias + h2f(X[(w*16+q*4+rg)*72 + col]);
    }
    float mu[4], rs[4];
    #pragma unroll
    for(int rg=0;rg<4;rg++){
      float sm=(y[0][rg]+y[1][rg])+(y[2][rg]+y[3][rg]);
      sm+=__shfl_xor(sm,1); sm+=__shfl_xor(sm,2); sm+=__shfl_xor(sm,4); sm+=__shfl_xor(sm,8);
      mu[rg]=sm*(1.f/64.f);
      float d0=y[0][rg]-mu[rg],d1=y[1][rg]-mu[rg],d2=y[2][rg]-mu[rg],d3=y[3][rg]-mu[rg];
      float vv=(d0*d0+d1*d1)+(d2*d2+d3*d3);
      vv+=__shfl_xor(vv,1); vv+=__shfl_xor(vv,2); vv+=__shfl_xor(vv,4); vv+=__shfl_xor(vv,8);
      rs[rg]=rsqrtf(vv*(1.f/64.f)+1e-5f);
    }
    #pragma unroll
    for(int nt=0;nt<4;nt++){
      int col=nt*16+m; float g=g1L[col], be=be1L[col];
      #pragma unroll
      for(int rg=0;rg<4;rg++){
        float v=(y[nt][rg]-mu[rg])*rs[rg]*g+be;
        y[nt][rg]=v;                                  // FF residual (f32)
        QKV[(w*16+q*4+rg)*72 + col]=f2h(v);           // y -> wave-own rows
      }
    }

    // ---- FF1: y A-frags; H -> pitch-136 overlay ----
    half8 ya0 = *(const half8*)&QKV[r*72 + q*8];
    half8 ya1 = *(const half8*)&QKV[r*72 + 32 + q*8];
    #pragma unroll
    for(int nt=0;nt<8;nt++){
      f32x4 acc={0.f,0.f,0.f,0.f};
      acc = __builtin_amdgcn_mfma_f32_16x16x32_f16(ya0, w1v[(nt*2+0)*64+lane], acc,0,0,0);
      acc = __builtin_amdgcn_mfma_f32_16x16x32_f16(ya1, w1v[(nt*2+1)*64+lane], acc,0,0,0);
      float bias=b1L[nt*16+m];
      #pragma unroll
      for(int rg=0;rg<4;rg++)
        Hd[(w*16+q*4+rg)*136 + nt*16+m] = f2h(fmaxf(acc[rg]+bias, 0.f));
    }

    // ---- FF2 + residual y + LN2 ----
    half8 ha[4];
    #pragma unroll
    for(int c=0;c<4;c++)
      ha[c] = *(const half8*)&Hd[r*136 + c*32 + q*8];
    #pragma unroll
    for(int nt=0;nt<4;nt++){
      f32x4 acc={0.f,0.f,0.f,0.f};
      #pragma unroll
      for(int c=0;c<4;c++)
        acc = __builtin_amdgcn_mfma_f32_16x16x32_f16(ha[c], w2v[(nt*4+c)*64+lane], acc,0,0,0);
      int col=nt*16+m; float bias=b2L[col];
      #pragma unroll
      for(int rg=0;rg<4;rg++)
        y[nt][rg] = acc[rg] + bias + y[nt][rg];
    }
    #pragma unroll
    for(int rg=0;rg<4;rg++){
      float sm=(y[0][rg]+y[1][rg])+(y[2][rg]+y[3][rg]);
      sm+=__shfl_xor(sm,1); sm+=__shfl_xor(sm,2); sm+=__shfl_xor(sm,4); sm+=__shfl_xor(sm,8);
      mu[rg]=sm*(1.f/64.f);
      float d0=y[0][rg]-mu[rg],d1=y[1][rg]-mu[rg],d2=y[2][rg]-mu[rg],d3=y[3][rg]-mu[rg];
      float vv=(d0*d0+d1*d1)+(d2*d2+d3*d3);
      vv+=__shfl_xor(vv,1); vv+=__shfl_xor(vv,2); vv+=__shfl_xor(vv,4); vv+=__shfl_xor(vv,8);
      rs[rg]=rsqrtf(vv*(1.f/64.f)+1e-5f);
    }
    if(l==0){
      #pragma unroll
      for(int nt=0;nt<4;nt++){
        int col=nt*16+m; float g=g2L[col], be=be2L[col];
        #pragma unroll
        for(int rg=0;rg<4;rg++)
          X[(w*16+q*4+rg)*72 + col] = f2h((y[nt][rg]-mu[rg])*rs[rg]*g + be);
      }
      __syncthreads();   // before next layer's QKV scatter overwrites QKV regions
    } else {
      // fused prediction head: rows with t==11 are rg==3 of exactly one
      // q-group per node; condition uniform over the 16-lane m-group.
      int rc = w*16 + q*4 + 3;
      int nn = rc/12;
      if(rc - nn*12 == 11){
        float vfin[4];
        #pragma unroll
        for(int nt=0;nt<4;nt++){
          int col=nt*16+m;
          vfin[nt] = (y[nt][3]-mu[3])*rs[3]*g2L[col] + be2L[col];
        }
        int gm = blockIdx.x*4 + nn;
        unsigned bb=(unsigned)gm/N_, n2=(unsigned)gm-bb*N_;
        #pragma unroll
        for(int h3=0;h3<3;h3++){
          float p = vfin[0]*Wh[h3*64+m]    + vfin[1]*Wh[h3*64+16+m]
                  + vfin[2]*Wh[h3*64+32+m] + vfin[3]*Wh[h3*64+48+m];
          p += __shfl_xor(p,1); p += __shfl_xor(p,2);
          p += __shfl_xor(p,4); p += __shfl_xor(p,8);
          if(m==0) out[(bb*3+h3)*N_+n2] = p + bh[h3];
        }
      }
    }
  }
}

extern "C" void kernel_launch(void* const* d_in, const int* in_sizes, int n_in,
                              void* d_out, int out_size, void* d_ws, size_t ws_size,
                              hipStream_t stream)
{
  const float* x_seq=(const float*)d_in[0];
  const int*   ei   =(const int*)d_in[1];
  const float* W1   =(const float*)d_in[2];
  const float* as1  =(const float*)d_in[3];
  const float* ad1  =(const float*)d_in[4];
  const float* b1   =(const float*)d_in[5];
  const float* W2   =(const float*)d_in[6];
  const float* as2  =(const float*)d_in[7];
  const float* ad2  =(const float*)d_in[8];
  const float* b2   =(const float*)d_in[9];
  const float* Wqkv =(const float*)d_in[10];
  const float* bqkv =(const float*)d_in[11];
  const float* Wo   =(const float*)d_in[12];
  const float* bo   =(const float*)d_in[13];
  const float* Wf1  =(const float*)d_in[14];
  const float* bf1p =(const float*)d_in[15];
  const float* Wf2  =(const float*)d_in[16];
  const float* bf2p =(const float*)d_in[17];
  const float* g1   =(const float*)d_in[18];
  const float* be1  =(const float*)d_in[19];
  const float* g2   =(const float*)d_in[20];
  const float* be2  =(const float*)d_in[21];
  const float* Wh   =(const float*)d_in[22];
  const float* bh   =(const float*)d_in[23];

  // workspace layout (~99 MB)
  u16* seqh   = (u16*)d_ws;                     // [T][M][64] f16  24,576,000 u16
  float* asc  = (float*)(seqh + 24576000);      // [T][M][4]        1,536,000 f
  float* adc  = asc + 1536000;                  //                  1,536,000 f
  u16* h2u    = (u16*)(adc + 1536000);          // [T][M][64]   24,576,000 u16
  u16* wqB    = h2u + 24576000;                 // 24576
  u16* woB    = wqB + 24576;                    // 8192
  u16* w1B    = woB + 8192;                     // 16384
  u16* w2B    = w1B + 16384;                    // 16384
  float* peT  = (float*)(w2B + 16384);          // 768
  u16* w2gB   = (u16*)(peT + 768);              // 2048
  int* deg    = (int*)(w2gB + 2048);            // 2000
  int* cursor = deg + N_;                       // 2000
  int* offs   = cursor + N_;                    // 2001
  int* csr    = offs + (N_ + 2);                // 10000 (one graph)

  k_prep   <<<dim3(268), dim3(256), 0, stream>>>(Wqkv, Wo, Wf1, Wf2, W2,
                                                 wqB, woB, w1B, w2B, peT, w2gB);

  // CSR build: ONE graph (edge list identical for all b and t)
  hipMemsetAsync(deg, 0, (size_t)2*N_*sizeof(int), stream);   // deg + cursor
  k_histg <<<dim3((EG+255)/256), dim3(256), 0, stream>>>(ei, deg);
  k_scang <<<dim3(1), dim3(1024), 0, stream>>>(deg, offs);
  k_scatg <<<dim3((EG+255)/256), dim3(256), 0, stream>>>(ei, offs, cursor, csr);

  k_gat12<<<dim3(500,T_), dim3(256), 0, stream>>>(x_seq, W1, as1, ad1, b1,
                                                  as2, ad2, offs, csr, w2gB,
                                                  h2u, asc, adc);
  k_gat2b<<<dim3(24000), dim3(256), 0, stream>>>(h2u, asc, adc, b2, offs, csr, peT, seqh);

  k_layer2<<<dim3(8000), dim3(192), 0, stream>>>(seqh,
      wqB, woB, w1B, w2B,
      bqkv, bo, bf1p, bf2p,
      g1, be1, g2, be2,
      Wh, bh, (float*)d_out);
}

// Round 19
// 332.475 us; speedup vs baseline: 1.0347x; 1.0347x over previous
//
#include <hip/hip_runtime.h>
#include <hip/hip_bf16.h>

#define B_ 16
#define T_ 12
#define N_ 2000
#define E_ 8000
#define M_ 32000                 // B_*N_
#define EG (E_ + N_)             // 10000 edges per graph incl self loops
#define D_ 64

typedef __hip_bfloat16 bf16;
typedef unsigned short u16;
typedef __attribute__((ext_vector_type(8))) _Float16 half8;
typedef __attribute__((ext_vector_type(2))) _Float16 h2v;
typedef __attribute__((ext_vector_type(4))) float f32x4;

__device__ __forceinline__ float bfu(u16 u){ return __uint_as_float(((unsigned int)u)<<16); }
__device__ __forceinline__ u16 f2bu(float f){
  unsigned int x = __float_as_uint(f);
  x += 0x7FFFu + ((x >> 16) & 1u);
  return (u16)(x >> 16);
}
__device__ __forceinline__ u16 f2h(float f){
  _Float16 h = (_Float16)f; u16 r; __builtin_memcpy(&r, &h, 2); return r;
}
__device__ __forceinline__ float h2f(u16 u){
  _Float16 h; __builtin_memcpy(&h, &u, 2); return (float)h;
}
__device__ __forceinline__ h2v u2h(unsigned u){ h2v r; __builtin_memcpy(&r,&u,4); return r; }

// bijective XCD-aware block swizzle (m204 form): contiguous work chunk per XCD.
__device__ __forceinline__ int xcd_swz(int x, int n){
  int q = n>>3, r = n&7;
  int xcd = x&7, idx = x>>3;
  int base = (xcd<r) ? xcd*(q+1) : r*(q+1) + (xcd-r)*q;
  return base + idx;
}

// ---------------- weight prep: f16 MFMA fragments + PE table ----------------
__global__ void k_prep(const float* __restrict__ Wqkv, const float* __restrict__ Wo,
                       const float* __restrict__ Wf1, const float* __restrict__ Wf2,
                       const float* __restrict__ W2g,
                       u16* __restrict__ wqB, u16* __restrict__ woB,
                       u16* __restrict__ w1B, u16* __restrict__ w2B,
                       float* __restrict__ peT, u16* __restrict__ w2gB){
  int i = blockIdx.x*256 + threadIdx.x;    // 268 blocks
  if(i < 24576){
    int l=i/12288, r=i-l*12288;
    int nt=r>>10, r2=r&1023, c=r2>>9, r3=r2&511, lane=r3>>3, jj=r3&7;
    int m=lane&15, q=lane>>4;
    wqB[i] = f2h(Wqkv[l*12288 + (nt*16+m)*64 + c*32 + q*8 + jj]);
  } else if(i < 32768){
    int k2=i-24576;
    int l=k2>>12, r=k2&4095;
    int nt=r>>10, r2=r&1023, c=r2>>9, r3=r2&511, lane=r3>>3, jj=r3&7;
    int m=lane&15, q=lane>>4;
    woB[k2] = f2h(Wo[l*4096 + (nt*16+m)*64 + c*32 + q*8 + jj]);
  } else if(i < 49152){
    int k2=i-32768;
    int l=k2>>13, r=k2&8191;
    int nt=r>>10, r2=r&1023, c=r2>>9, r3=r2&511, lane=r3>>3, jj=r3&7;
    int m=lane&15, q=lane>>4;
    w1B[k2] = f2h(Wf1[l*8192 + (nt*16+m)*64 + c*32 + q*8 + jj]);
  } else if(i < 65536){
    int k2=i-49152;
    int l=k2>>13, r=k2&8191;
    int nt=r>>11, r2=r&2047, c=r2>>9, r3=r2&511, lane=r3>>3, jj=r3&7;
    int m=lane&15, q=lane>>4;
    w2B[k2] = f2h(Wf2[l*8192 + (nt*16+m)*128 + c*32 + q*8 + jj]);
  } else {
    int i2 = i - 65536;
    if(i2 < 768){
      int t=i2>>6, ch=i2&63;
      float ang = (float)t * __expf(-0.14391156463f * (float)(ch & ~1));
      peT[i2] = (ch&1) ? __cosf(ang) : __sinf(ang);
    } else if(i2 < 768+2048){
      // GAT2 W2 [32][64] as dual frags: elem j = W2[q*8+j][nt*16+m]
      int i3 = i2-768;
      int nt=i3>>9, r=i3&511, lane=r>>3, j=r&7;
      int m=lane&15, q=lane>>4;
      w2gB[i3] = f2h(W2g[(q*8+j)*64 + nt*16 + m]);
    }
  }
}

// ---------------- CSR build (ONE graph -- identical for all b,t) ----------------
__global__ void k_histg(const int* __restrict__ ei, int* __restrict__ deg){
  int e = blockIdx.x*256 + threadIdx.x; if(e>=EG) return;
  int dst = (e < E_) ? ei[E_+e] : e - E_;
  atomicAdd(&deg[dst], 1);
}

// single-block inclusive scan over 2000 degrees -> offs[0..2000]
__global__ __launch_bounds__(1024) void k_scang(const int* __restrict__ deg, int* __restrict__ offs){
  __shared__ int s[2048];
  int tid = threadIdx.x;
  s[tid]      = (tid      < N_) ? deg[tid]      : 0;
  s[tid+1024] = (tid+1024 < N_) ? deg[tid+1024] : 0;
  __syncthreads();
  for(int off=1; off<2048; off<<=1){
    int a0 = (tid>=off)      ? s[tid-off]      : 0;
    int a1 = (tid+1024>=off) ? s[tid+1024-off] : 0;
    __syncthreads();
    s[tid] += a0; s[tid+1024] += a1;
    __syncthreads();
  }
  if(tid      < N_) offs[tid+1]      = s[tid];
  if(tid+1024 < N_) offs[tid+1024+1] = s[tid+1024];
  if(tid==0) offs[0]=0;
}

__global__ void k_scatg(const int* __restrict__ ei, const int* __restrict__ offs,
                        int* __restrict__ cursor, int* __restrict__ csr){
  int e = blockIdx.x*256 + threadIdx.x; if(e>=EG) return;
  int srcl, dst;
  if(e < E_){ srcl = ei[e]; dst = ei[E_+e]; }
  else      { srcl = e - E_; dst = e - E_; }
  int pos = atomicAdd(&cursor[dst], 1);
  csr[offs[dst]+pos] = srcl;
}

// ---------------- fused GAT1 + GAT2 feature/score (MFMA) ----------------
// Round-11 measured form (UNCHANGED). Lane q*16+m: node m, head q; edge loop
// 4-way over q-lanes; operand-swapped MFMAs; packed stores; XCD swizzle.
__global__ __launch_bounds__(256) void k_gat12(
  const float* __restrict__ x_seq, const float* __restrict__ W1,
  const float* __restrict__ as1, const float* __restrict__ ad1, const float* __restrict__ b1,
  const float* __restrict__ as2, const float* __restrict__ ad2,
  const int* __restrict__ offs, const int* __restrict__ csr,
  const u16* __restrict__ w2gB,
  u16* __restrict__ h2u, float* __restrict__ asc, float* __restrict__ adc)
{
  int tid = threadIdx.x, w = tid>>6, lane = tid&63;
  int m = lane&15, q = lane>>4;
  int t = blockIdx.y;
  int bx = xcd_swz(blockIdx.x, 500);
  int node = bx*64 + w*16 + m;
  unsigned un=(unsigned)node, b=un/N_, n=un-b*N_;

  const half8* wb = (const half8*)w2gB;
  half8 w2f0 = wb[0*64+lane], w2f1 = wb[1*64+lane],
        w2f2 = wb[2*64+lane], w2f3 = wb[3*64+lane];

  float sS[4], sD[4];
  #pragma unroll
  for(int h=0;h<4;h++){
    float a=0.f, d=0.f;
    #pragma unroll
    for(int c=0;c<8;c++){ float wv=W1[h*8+c]; a+=wv*as1[h*8+c]; d+=wv*ad1[h*8+c]; }
    sS[h]=a; sD[h]=d;
  }

  const float* xsl = x_seq + (size_t)(b*T_+t)*N_;
  float xm = xsl[n];
  int e0=offs[n], e1=offs[n+1];
  float sum[4]={0.f,0.f,0.f,0.f}, ax[4]={0.f,0.f,0.f,0.f};
  for(int e=e0+q; e<e1; e+=4){
    float xv = xsl[csr[e]];
    #pragma unroll
    for(int h=0;h<4;h++){
      float ee = xv*sS[h] + xm*sD[h]; ee = ee>0.f ? ee : 0.2f*ee;
      float wv = __expf(ee); sum[h]+=wv; ax[h]+=wv*xv;
    }
  }
  #pragma unroll
  for(int h=0;h<4;h++){
    sum[h] += __shfl_xor(sum[h],16); sum[h] += __shfl_xor(sum[h],32);
    ax[h]  += __shfl_xor(ax[h],16);  ax[h]  += __shfl_xor(ax[h],32);
  }
  float A = ax[q]/(sum[q]+1e-16f);

  half8 af;
  #pragma unroll
  for(int j=0;j<8;j++){
    float v = A*W1[q*8+j] + b1[q*8+j]; v = v>0.f?v:0.f;
    af[j] = (_Float16)v;
  }
  f32x4 ac0={0.f,0.f,0.f,0.f}, ac1=ac0, ac2=ac0, ac3=ac0;
  ac0 = __builtin_amdgcn_mfma_f32_16x16x32_f16(w2f0, af, ac0,0,0,0);
  ac1 = __builtin_amdgcn_mfma_f32_16x16x32_f16(w2f1, af, ac1,0,0,0);
  ac2 = __builtin_amdgcn_mfma_f32_16x16x32_f16(w2f2, af, ac2,0,0,0);
  ac3 = __builtin_amdgcn_mfma_f32_16x16x32_f16(w2f3, af, ac3,0,0,0);

  size_t nd = (size_t)t*M_ + node;
  u16* row = h2u + nd*64;
  {
    uint2 p;
    p.x = (unsigned)f2bu(ac0[0]) | ((unsigned)f2bu(ac0[1])<<16);
    p.y = (unsigned)f2bu(ac0[2]) | ((unsigned)f2bu(ac0[3])<<16);
    *(uint2*)(row + 0*16 + q*4) = p;
    p.x = (unsigned)f2bu(ac1[0]) | ((unsigned)f2bu(ac1[1])<<16);
    p.y = (unsigned)f2bu(ac1[2]) | ((unsigned)f2bu(ac1[3])<<16);
    *(uint2*)(row + 1*16 + q*4) = p;
    p.x = (unsigned)f2bu(ac2[0]) | ((unsigned)f2bu(ac2[1])<<16);
    p.y = (unsigned)f2bu(ac2[2]) | ((unsigned)f2bu(ac2[3])<<16);
    *(uint2*)(row + 2*16 + q*4) = p;
    p.x = (unsigned)f2bu(ac3[0]) | ((unsigned)f2bu(ac3[1])<<16);
    p.y = (unsigned)f2bu(ac3[2]) | ((unsigned)f2bu(ac3[3])<<16);
    *(uint2*)(row + 3*16 + q*4) = p;
  }

  const float* a2sp = as2 + q*4;
  const float* a2dp = ad2 + q*4;
  float ps[4], pd[4];
  ps[0]=ac0[0]*a2sp[ 0]+ac0[1]*a2sp[ 1]+ac0[2]*a2sp[ 2]+ac0[3]*a2sp[ 3];
  ps[1]=ac1[0]*a2sp[16]+ac1[1]*a2sp[17]+ac1[2]*a2sp[18]+ac1[3]*a2sp[19];
  ps[2]=ac2[0]*a2sp[32]+ac2[1]*a2sp[33]+ac2[2]*a2sp[34]+ac2[3]*a2sp[35];
  ps[3]=ac3[0]*a2sp[48]+ac3[1]*a2sp[49]+ac3[2]*a2sp[50]+ac3[3]*a2sp[51];
  pd[0]=ac0[0]*a2dp[ 0]+ac0[1]*a2dp[ 1]+ac0[2]*a2dp[ 2]+ac0[3]*a2dp[ 3];
  pd[1]=ac1[0]*a2dp[16]+ac1[1]*a2dp[17]+ac1[2]*a2dp[18]+ac1[3]*a2dp[19];
  pd[2]=ac2[0]*a2dp[32]+ac2[1]*a2dp[33]+ac2[2]*a2dp[34]+ac2[3]*a2dp[35];
  pd[3]=ac3[0]*a2dp[48]+ac3[1]*a2dp[49]+ac3[2]*a2dp[50]+ac3[3]*a2dp[51];
  #pragma unroll
  for(int h=0;h<4;h++){
    ps[h] += __shfl_xor(ps[h],16); ps[h] += __shfl_xor(ps[h],32);
    pd[h] += __shfl_xor(pd[h],16); pd[h] += __shfl_xor(pd[h],32);
  }
  float ra = (q&1) ? ((q&2)? ps[3]:ps[1]) : ((q&2)? ps[2]:ps[0]);
  float rd = (q&1) ? ((q&2)? pd[3]:pd[1]) : ((q&2)? pd[2]:pd[0]);
  asc[nd*4+q] = ra;
  adc[nd*4+q] = rd;
}

// ---------------- GAT2 softmax-aggregate + bias + relu + PE(table); f16 out ------
// Round-13 slice-major XCD mapping; lane-pair (2-way) edge split -- measured
// optimum. 4-way split (r18) regressed +10us (merge+redundant-gather overhead
// outweighs chain cut); width-4 gathers (r6) null; locality (r9/r13) saturated.
__global__ __launch_bounds__(256) void k_gat2b(
  const u16* __restrict__ h2u, const float* __restrict__ asc, const float* __restrict__ adc,
  const float* __restrict__ b2, const int* __restrict__ offs, const int* __restrict__ csr,
  const float* __restrict__ peT, u16* __restrict__ seq)
{
  int x = blockIdx.x;
  int xcd = x&7, idx = x>>3;          // idx in [0,1512)
  int work = xcd*1512 + idx;          // contiguous slice-major work per XCD
  int slice = work/63;                // [0,192)
  int local = work - slice*63;        // [0,63)
  int b = slice/12, t = slice - b*12;
  int tid = threadIdx.x;
  int nl = local*32 + (tid>>3);       // local node in [0,2016)
  if(nl >= N_) return;                // uniform per 8-lane task group
  int j = (tid>>2)&1, h = tid&3;

  size_t base_s = (size_t)t*M_ + (size_t)b*N_;   // csr holds local indices
  float am = adc[(base_s + nl)*4+h];
  int e0=offs[nl], e1=offs[nl+1];
  float sum=0.f;
  float A[16];
  #pragma unroll
  for(int c=0;c<16;c++) A[c]=0.f;
  for(int e=e0+j; e<e1; e+=2){
    size_t s = base_s + (unsigned)csr[e];
    float w = asc[s*4+h] + am; w = w>0.f ? w : 0.2f*w;
    w = __expf(w); sum += w;
    const uint4* hp = (const uint4*)(h2u + s*64 + h*16);
    uint4 p0 = hp[0], p1 = hp[1];
    A[ 0] += w*bfu((u16)(p0.x)); A[ 1] += w*bfu((u16)(p0.x>>16));
    A[ 2] += w*bfu((u16)(p0.y)); A[ 3] += w*bfu((u16)(p0.y>>16));
    A[ 4] += w*bfu((u16)(p0.z)); A[ 5] += w*bfu((u16)(p0.z>>16));
    A[ 6] += w*bfu((u16)(p0.w)); A[ 7] += w*bfu((u16)(p0.w>>16));
    A[ 8] += w*bfu((u16)(p1.x)); A[ 9] += w*bfu((u16)(p1.x>>16));
    A[10] += w*bfu((u16)(p1.y)); A[11] += w*bfu((u16)(p1.y>>16));
    A[12] += w*bfu((u16)(p1.z)); A[13] += w*bfu((u16)(p1.z>>16));
    A[14] += w*bfu((u16)(p1.w)); A[15] += w*bfu((u16)(p1.w>>16));
  }
  // merge the two edge-halves (partner lane: tid xor 4, same task group)
  sum += __shfl_xor(sum,4);
  #pragma unroll
  for(int c=0;c<16;c++) A[c] += __shfl_xor(A[c],4);

  float inv = 1.f/(sum + 1e-16f);
  u16 ov[8];
  #pragma unroll
  for(int c=0;c<8;c++){
    int ch = h*16 + j*8 + c;
    float v = A[j*8+c]*inv + b2[ch]; v = v>0.f ? v : 0.f;
    ov[c] = f2h(v + peT[t*64+ch]);
  }
  uint4 o;
  o.x = (unsigned)ov[0] | ((unsigned)ov[1]<<16);
  o.y = (unsigned)ov[2] | ((unsigned)ov[3]<<16);
  o.z = (unsigned)ov[4] | ((unsigned)ov[5]<<16);
  o.w = (unsigned)ov[6] | ((unsigned)ov[7]<<16);
  *(uint4*)(seq + (base_s + nl)*64 + h*16 + j*8) = o;
}

// ---------------- BOTH transformer layers + fused head -------------------------
// Round-15 measured optimum: __launch_bounds__(192,4) (VGPR 64, occ 38%,
// 168us steady). Weight-LDS-staging (r16): occ 16% -> 275us -- kernel is
// latency/occupancy-bound; do NOT add LDS or registers. Operand swap (x2),
// xres registers, gat2b fusion all regressed. Body UNCHANGED since round 4.
__global__ __launch_bounds__(192, 4) void k_layer2(
  const u16* __restrict__ seq,
  const u16* __restrict__ wqB, const u16* __restrict__ woB,
  const u16* __restrict__ w1B, const u16* __restrict__ w2B,
  const float* __restrict__ bqkv, const float* __restrict__ bo,
  const float* __restrict__ bf1,  const float* __restrict__ bf2,
  const float* __restrict__ g1,   const float* __restrict__ be1,
  const float* __restrict__ g2,   const float* __restrict__ be2,
  const float* __restrict__ Wh,   const float* __restrict__ bh,
  float* __restrict__ out)
{
  __shared__ __align__(16) u16 X[3456];      // [48][72] f16
  __shared__ __align__(16) u16 QKV[10368];   // [3][48][72]
  u16* Hd = QKV + 3456;                      // H[48][136] overlays K,V
  int tid=threadIdx.x, w=tid>>6, lane=tid&63;
  int m=lane&15, q=lane>>4;
  int r = w*16 + m;

  // stage X: wave w loads its own 16 rows (wave-private, no barrier needed).
  #pragma unroll
  for(int half=0; half<2; half++){
    int rr = half*8 + (lane>>3);
    int row = w*16 + rr;
    int nn = row/12, tt = row-nn*12;
    const uint4* src = (const uint4*)(seq + ((size_t)tt*M_ + (size_t)blockIdx.x*4+nn)*64) + (lane&7);
    *((uint4*)&X[row*72] + (lane&7)) = *src;
  }

  #pragma unroll 1
  for(int l=0; l<2; l++){
    const half8* wqv = (const half8*)(wqB + (size_t)l*12288);
    const half8* wov = (const half8*)(woB + (size_t)l*4096);
    const half8* w1v = (const half8*)(w1B + (size_t)l*8192);
    const half8* w2v = (const half8*)(w2B + (size_t)l*8192);
    const float* bq = bqkv + l*192;
    const float* boL = bo + l*64;
    const float* b1L = bf1 + l*128;
    const float* b2L = bf2 + l*64;
    const float* g1L = g1 + l*64, *be1L = be1 + l*64;
    const float* g2L = g2 + l*64, *be2L = be2 + l*64;

    // ---- QKV projection: A-frags from X (wave-own rows) ----
    half8 xa0 = *(const half8*)&X[r*72 + q*8];
    half8 xa1 = *(const half8*)&X[r*72 + 32 + q*8];
    #pragma unroll
    for(int nt=0; nt<12; nt++){
      f32x4 acc={0.f,0.f,0.f,0.f};
      acc = __builtin_amdgcn_mfma_f32_16x16x32_f16(xa0, wqv[(nt*2+0)*64+lane], acc,0,0,0);
      acc = __builtin_amdgcn_mfma_f32_16x16x32_f16(xa1, wqv[(nt*2+1)*64+lane], acc,0,0,0);
      int cg = nt*16+m; float bias = bq[cg];
      int s = nt>>2, lc = cg&63;
      #pragma unroll
      for(int rg=0;rg<4;rg++){
        int row = w*16 + q*4 + rg;
        QKV[s*3456 + row*72 + lc] = f2h(acc[rg]+bias);
      }
    }
    __syncthreads();

    // ---- attention: 192 lanes = (node an, head ah, time at); fdot2 + pk_fma ----
    {
      int an = tid/48, rem = tid - an*48;
      int ah = rem/12, at = rem - ah*12;
      u16* qrow = &QKV[(an*12+at)*72 + ah*16];
      uint4 qa = ((const uint4*)qrow)[0], qb = ((const uint4*)qrow)[1];
      float s[12];
      #pragma unroll
      for(int t2=0;t2<12;t2++){
        const uint4* kp = (const uint4*)&QKV[3456 + (an*12+t2)*72 + ah*16];
        uint4 ka=kp[0], kb=kp[1];
        float d=0.f;
        d=__builtin_amdgcn_fdot2(u2h(qa.x),u2h(ka.x),d,false);
        d=__builtin_amdgcn_fdot2(u2h(qa.y),u2h(ka.y),d,false);
        d=__builtin_amdgcn_fdot2(u2h(qa.z),u2h(ka.z),d,false);
        d=__builtin_amdgcn_fdot2(u2h(qa.w),u2h(ka.w),d,false);
        d=__builtin_amdgcn_fdot2(u2h(qb.x),u2h(kb.x),d,false);
        d=__builtin_amdgcn_fdot2(u2h(qb.y),u2h(kb.y),d,false);
        d=__builtin_amdgcn_fdot2(u2h(qb.z),u2h(kb.z),d,false);
        d=__builtin_amdgcn_fdot2(u2h(qb.w),u2h(kb.w),d,false);
        s[t2] = d*0.25f;
      }
      float mx=s[0];
      #pragma unroll
      for(int t2=1;t2<12;t2++) mx=fmaxf(mx,s[t2]);
      float sum=0.f;
      #pragma unroll
      for(int t2=0;t2<12;t2++){ s[t2]=__expf(s[t2]-mx); sum+=s[t2]; }
      float inv=1.f/sum;
      half8 o0, o1;
      #pragma unroll
      for(int i=0;i<8;i++){ o0[i]=(_Float16)0.f; o1[i]=(_Float16)0.f; }
      #pragma unroll
      for(int t2=0;t2<12;t2++){
        const half8* vr = (const half8*)&QKV[6912 + (an*12+t2)*72 + ah*16];
        _Float16 wh = (_Float16)s[t2];
        o0 += vr[0]*wh; o1 += vr[1]*wh;
      }
      _Float16 ih = (_Float16)inv;
      ((half8*)qrow)[0]=o0*ih; ((half8*)qrow)[1]=o1*ih;
    }
    __syncthreads();

    // ---- Wo + residual(X) + LN1 ----
    half8 oa0 = *(const half8*)&QKV[r*72 + q*8];
    half8 oa1 = *(const half8*)&QKV[r*72 + 32 + q*8];
    float y[4][4];
    #pragma unroll
    for(int nt=0;nt<4;nt++){
      f32x4 acc={0.f,0.f,0.f,0.f};
      acc = __builtin_amdgcn_mfma_f32_16x16x32_f16(oa0, wov[(nt*2+0)*64+lane], acc,0,0,0);
      acc = __builtin_amdgcn_mfma_f32_16x16x32_f16(oa1, wov[(nt*2+1)*64+lane], acc,0,0,0);
      int col=nt*16+m; float bias=boL[col];
      #pragma unroll
      for(int rg=0;rg<4;rg++)
        y[nt][rg] = acc[rg] + bias + h2f(X[(w*16+q*4+rg)*72 + col]);
    }
    float mu[4], rs[4];
    #pragma unroll
    for(int rg=0;rg<4;rg++){
      float sm=(y[0][rg]+y[1][rg])+(y[2][rg]+y[3][rg]);
      sm+=__shfl_xor(sm,1); sm+=__shfl_xor(sm,2); sm+=__shfl_xor(sm,4); sm+=__shfl_xor(sm,8);
      mu[rg]=sm*(1.f/64.f);
      float d0=y[0][rg]-mu[rg],d1=y[1][rg]-mu[rg],d2=y[2][rg]-mu[rg],d3=y[3][rg]-mu[rg];
      float vv=(d0*d0+d1*d1)+(d2*d2+d3*d3);
      vv+=__shfl_xor(vv,1); vv+=__shfl_xor(vv,2); vv+=__shfl_xor(vv,4); vv+=__shfl_xor(vv,8);
      rs[rg]=rsqrtf(vv*(1.f/64.f)+1e-5f);
    }
    #pragma unroll
    for(int nt=0;nt<4;nt++){
      int col=nt*16+m; float g=g1L[col], be=be1L[col];
      #pragma unroll
      for(int rg=0;rg<4;rg++){
        float v=(y[nt][rg]-mu[rg])*rs[rg]*g+be;
        y[nt][rg]=v;                                  // FF residual (f32)
        QKV[(w*16+q*4+rg)*72 + col]=f2h(v);           // y -> wave-own rows
      }
    }

    // ---- FF1: y A-frags; H -> pitch-136 overlay ----
    half8 ya0 = *(const half8*)&QKV[r*72 + q*8];
    half8 ya1 = *(const half8*)&QKV[r*72 + 32 + q*8];
    #pragma unroll
    for(int nt=0;nt<8;nt++){
      f32x4 acc={0.f,0.f,0.f,0.f};
      acc = __builtin_amdgcn_mfma_f32_16x16x32_f16(ya0, w1v[(nt*2+0)*64+lane], acc,0,0,0);
      acc = __builtin_amdgcn_mfma_f32_16x16x32_f16(ya1, w1v[(nt*2+1)*64+lane], acc,0,0,0);
      float bias=b1L[nt*16+m];
      #pragma unroll
      for(int rg=0;rg<4;rg++)
        Hd[(w*16+q*4+rg)*136 + nt*16+m] = f2h(fmaxf(acc[rg]+bias, 0.f));
    }

    // ---- FF2 + residual y + LN2 ----
    half8 ha[4];
    #pragma unroll
    for(int c=0;c<4;c++)
      ha[c] = *(const half8*)&Hd[r*136 + c*32 + q*8];
    #pragma unroll
    for(int nt=0;nt<4;nt++){
      f32x4 acc={0.f,0.f,0.f,0.f};
      #pragma unroll
      for(int c=0;c<4;c++)
        acc = __builtin_amdgcn_mfma_f32_16x16x32_f16(ha[c], w2v[(nt*4+c)*64+lane], acc,0,0,0);
      int col=nt*16+m; float bias=b2L[col];
      #pragma unroll
      for(int rg=0;rg<4;rg++)
        y[nt][rg] = acc[rg] + bias + y[nt][rg];
    }
    #pragma unroll
    for(int rg=0;rg<4;rg++){
      float sm=(y[0][rg]+y[1][rg])+(y[2][rg]+y[3][rg]);
      sm+=__shfl_xor(sm,1); sm+=__shfl_xor(sm,2); sm+=__shfl_xor(sm,4); sm+=__shfl_xor(sm,8);
      mu[rg]=sm*(1.f/64.f);
      float d0=y[0][rg]-mu[rg],d1=y[1][rg]-mu[rg],d2=y[2][rg]-mu[rg],d3=y[3][rg]-mu[rg];
      float vv=(d0*d0+d1*d1)+(d2*d2+d3*d3);
      vv+=__shfl_xor(vv,1); vv+=__shfl_xor(vv,2); vv+=__shfl_xor(vv,4); vv+=__shfl_xor(vv,8);
      rs[rg]=rsqrtf(vv*(1.f/64.f)+1e-5f);
    }
    if(l==0){
      #pragma unroll
      for(int nt=0;nt<4;nt++){
        int col=nt*16+m; float g=g2L[col], be=be2L[col];
        #pragma unroll
        for(int rg=0;rg<4;rg++)
          X[(w*16+q*4+rg)*72 + col] = f2h((y[nt][rg]-mu[rg])*rs[rg]*g + be);
      }
      __syncthreads();   // before next layer's QKV scatter overwrites QKV regions
    } else {
      // fused prediction head: rows with t==11 are rg==3 of exactly one
      // q-group per node; condition uniform over the 16-lane m-group.
      int rc = w*16 + q*4 + 3;
      int nn = rc/12;
      if(rc - nn*12 == 11){
        float vfin[4];
        #pragma unroll
        for(int nt=0;nt<4;nt++){
          int col=nt*16+m;
          vfin[nt] = (y[nt][3]-mu[3])*rs[3]*g2L[col] + be2L[col];
        }
        int gm = blockIdx.x*4 + nn;
        unsigned bb=(unsigned)gm/N_, n2=(unsigned)gm-bb*N_;
        #pragma unroll
        for(int h3=0;h3<3;h3++){
          float p = vfin[0]*Wh[h3*64+m]    + vfin[1]*Wh[h3*64+16+m]
                  + vfin[2]*Wh[h3*64+32+m] + vfin[3]*Wh[h3*64+48+m];
          p += __shfl_xor(p,1); p += __shfl_xor(p,2);
          p += __shfl_xor(p,4); p += __shfl_xor(p,8);
          if(m==0) out[(bb*3+h3)*N_+n2] = p + bh[h3];
        }
      }
    }
  }
}

extern "C" void kernel_launch(void* const* d_in, const int* in_sizes, int n_in,
                              void* d_out, int out_size, void* d_ws, size_t ws_size,
                              hipStream_t stream)
{
  const float* x_seq=(const float*)d_in[0];
  const int*   ei   =(const int*)d_in[1];
  const float* W1   =(const float*)d_in[2];
  const float* as1  =(const float*)d_in[3];
  const float* ad1  =(const float*)d_in[4];
  const float* b1   =(const float*)d_in[5];
  const float* W2   =(const float*)d_in[6];
  const float* as2  =(const float*)d_in[7];
  const float* ad2  =(const float*)d_in[8];
  const float* b2   =(const float*)d_in[9];
  const float* Wqkv =(const float*)d_in[10];
  const float* bqkv =(const float*)d_in[11];
  const float* Wo   =(const float*)d_in[12];
  const float* bo   =(const float*)d_in[13];
  const float* Wf1  =(const float*)d_in[14];
  const float* bf1p =(const float*)d_in[15];
  const float* Wf2  =(const float*)d_in[16];
  const float* bf2p =(const float*)d_in[17];
  const float* g1   =(const float*)d_in[18];
  const float* be1  =(const float*)d_in[19];
  const float* g2   =(const float*)d_in[20];
  const float* be2  =(const float*)d_in[21];
  const float* Wh   =(const float*)d_in[22];
  const float* bh   =(const float*)d_in[23];

  // workspace layout (~99 MB)
  u16* seqh   = (u16*)d_ws;                     // [T][M][64] f16  24,576,000 u16
  float* asc  = (float*)(seqh + 24576000);      // [T][M][4]        1,536,000 f
  float* adc  = asc + 1536000;                  //                  1,536,000 f
  u16* h2u    = (u16*)(adc + 1536000);          // [T][M][64]   24,576,000 u16
  u16* wqB    = h2u + 24576000;                 // 24576
  u16* woB    = wqB + 24576;                    // 8192
  u16* w1B    = woB + 8192;                     // 16384
  u16* w2B    = w1B + 16384;                    // 16384
  float* peT  = (float*)(w2B + 16384);          // 768
  u16* w2gB   = (u16*)(peT + 768);              // 2048
  int* deg    = (int*)(w2gB + 2048);            // 2000
  int* cursor = deg + N_;                       // 2000
  int* offs   = cursor + N_;                    // 2001
  int* csr    = offs + (N_ + 2);                // 10000 (one graph)

  k_prep   <<<dim3(268), dim3(256), 0, stream>>>(Wqkv, Wo, Wf1, Wf2, W2,
                                                 wqB, woB, w1B, w2B, peT, w2gB);

  // CSR build: ONE graph (edge list identical for all b and t)
  hipMemsetAsync(deg, 0, (size_t)2*N_*sizeof(int), stream);   // deg + cursor
  k_histg <<<dim3((EG+255)/256), dim3(256), 0, stream>>>(ei, deg);
  k_scang <<<dim3(1), dim3(1024), 0, stream>>>(deg, offs);
  k_scatg <<<dim3((EG+255)/256), dim3(256), 0, stream>>>(ei, offs, cursor, csr);

  k_gat12<<<dim3(500,T_), dim3(256), 0, stream>>>(x_seq, W1, as1, ad1, b1,
                                                  as2, ad2, offs, csr, w2gB,
                                                  h2u, asc, adc);
  k_gat2b<<<dim3(12096), dim3(256), 0, stream>>>(h2u, asc, adc, b2, offs, csr, peT, seqh);

  k_layer2<<<dim3(8000), dim3(192), 0, stream>>>(seqh,
      wqB, woB, w1B, w2B,
      bqkv, bo, bf1p, bf2p,
      g1, be1, g2, be2,
      Wh, bh, (float*)d_out);
}